// Round 10
// baseline (126.037 us; speedup 1.0000x reference)
//
#include <hip/hip_runtime.h>
#include <stdint.h>

// C = binarize(X) @ binarize(W), exact via MX-fp4 (+-1) scaled MFMA.
// X: 8192x4096 f32, W: 4096x4096 f32, C: 8192x4096 f32.
// fp4 e2m1: +1.0 = 0x2, -1.0 = 0xA. Scale E8M0 127 = 1.0 (word 0x7F7F7F7F).
//
// R10: R9's ring-of-4 counted-vmcnt pipeline with the STAGING LAYOUT BUG
// fixed. R9 failed because global_load_lds writes at wave-uniform base +
// lane*16 (per-lane LDS dest ignored, G21/m104); its dst0=tid*32 gave lane
// stride 32 -> scrambled LDS. Legal form (as in passing R5-R8): dest =
// bufOff + tid*16 + chunk*8192, i.e. thread -> row tid>>2, phys slot tid&3,
// chunks {A rows 0-127, A rows 128-255, B rows 0-127, B rows 128-255}.
// Swizzle (64B rows): phys_slot p holds logical p ^ ((row>>1)&3); applied as
// pre-swizzled GLOBAL source (fS=(tid>>3)&3) + XOR on the read side (fR).
// Pipeline: stage tile t+3 while computing t; per-tile sync = s_waitcnt
// vmcnt(8) + raw s_barrier (never vmcnt(0) in main loop); sched_barrier(0)
// fences pin issue groups so vmcnt counts stay exact.
#define MDIM 8192
#define NDIM 4096
#define KDIM 4096
#define KB2  (KDIM / 2)     // 2048 B per packed row (2 fp4/byte)
#define BKB  64             // K-tile bytes = 128 fp4 elems
#define NT   (KDIM / 128)   // 32 K-tiles

#define BM 256
#define BN 256
#define BUFSZ 32768         // A 256x64B (16 KiB) + B 256x64B (16 KiB)

typedef __attribute__((ext_vector_type(4))) int   i32x4;
typedef __attribute__((ext_vector_type(8))) int   i32x8;
typedef __attribute__((ext_vector_type(4))) float f32x4;

__device__ __forceinline__ void gload16(const void* g, void* l) {
    __builtin_amdgcn_global_load_lds(
        (const __attribute__((address_space(1))) void*)g,
        (__attribute__((address_space(3))) void*)l, 16, 0, 0);
}

__device__ __forceinline__ i32x8 pad8(i32x4 v) {
    i32x8 r;
    r[0] = v[0]; r[1] = v[1]; r[2] = v[2]; r[3] = v[3];
    r[4] = 0;    r[5] = 0;    r[6] = 0;    r[7] = 0;
    return r;
}

// scale 1.0 everywhere; fp4 format code = 4 for both operands.
#define MFMA_FP4(a, b, c)                                                   \
    __builtin_amdgcn_mfma_scale_f32_16x16x128_f8f6f4(                        \
        (a), (b), (c), 4, 4, 0, 0x7F7F7F7F, 0, 0x7F7F7F7F)

// ---------------- pack X -> A4 [M][K/2] fp4 nibbles (BW-bound) ---------------
__global__ __launch_bounds__(256) void pack_a4_kernel(const float* __restrict__ X,
                                                      uint8_t* __restrict__ A4) {
    size_t gt = (size_t)blockIdx.x * 256 + threadIdx.x;
    const float4* x4 = (const float4*)X + gt * 4;
    uint32_t out[2] = {0, 0};
#pragma unroll
    for (int q = 0; q < 4; ++q) {
        float4 v = x4[q];
        uint32_t b0 = (v.x >= 0.f ? 0x2u : 0xAu) | ((v.y >= 0.f ? 0x2u : 0xAu) << 4);
        uint32_t b1 = (v.z >= 0.f ? 0x2u : 0xAu) | ((v.w >= 0.f ? 0x2u : 0xAu) << 4);
        out[q >> 1] |= (b0 | (b1 << 8)) << ((q & 1) * 16);
    }
    ((uint2*)A4)[gt] = make_uint2(out[0], out[1]);
}

// ---------------- pack W -> B4T [N][K/2] fp4 nibbles, transposed -------------
__global__ __launch_bounds__(256) void pack_b4t_kernel(const float* __restrict__ W,
                                                       uint8_t* __restrict__ B4) {
    __shared__ uint8_t t[64][72];                 // sign nibbles, +8 pad
    const int tid = threadIdx.x;
    const int k0 = blockIdx.y * 64, n0 = blockIdx.x * 64;
#pragma unroll
    for (int r = 0; r < 4; ++r) {
        int e  = r * 1024 + tid * 4;
        int k  = e >> 6;
        int nn = e & 63;
        float4 v = *(const float4*)&W[(size_t)(k0 + k) * NDIM + n0 + nn];
        uint32_t b0 = (v.x >= 0.f) ? 0x2u : 0xAu;
        uint32_t b1 = (v.y >= 0.f) ? 0x2u : 0xAu;
        uint32_t b2 = (v.z >= 0.f) ? 0x2u : 0xAu;
        uint32_t b3 = (v.w >= 0.f) ? 0x2u : 0xAu;
        *(uint32_t*)&t[k][nn] = b0 | (b1 << 8) | (b2 << 16) | (b3 << 24);
    }
    __syncthreads();
    const int n = tid >> 2, kc = tid & 3;         // 16 k-elems -> 8 bytes each
    uint32_t w[2] = {0, 0};
#pragma unroll
    for (int b = 0; b < 8; ++b) {
        int k = kc * 16 + b * 2;
        uint32_t byte = (uint32_t)t[k][n] | ((uint32_t)t[k + 1][n] << 4);
        w[b >> 2] |= byte << ((b & 3) * 8);
    }
    *(uint2*)&B4[(size_t)(n0 + n) * KB2 + k0 / 2 + kc * 8] = make_uint2(w[0], w[1]);
}

// ---------------- main: fp4 MFMA GEMM, 256x256, ring-4 counted-vmcnt ---------
__global__ __launch_bounds__(512, 2) void binmm_fp4_kernel(const uint8_t* __restrict__ A4,
                                                           const uint8_t* __restrict__ B4,
                                                           float* __restrict__ C) {
    __shared__ uint8_t lds[4 * BUFSZ];            // 128 KiB

    const int tid = threadIdx.x, lane = tid & 63, wid = tid >> 6;
    const int wr = wid >> 2, wc = wid & 3;        // 2x4 waves; wave tile 128x64
    const int l15 = lane & 15, g = (lane >> 4) & 3;
    const int m0 = blockIdx.y * BM, n0 = blockIdx.x * BN;

    // ---- staging (LEGAL gload_lds form): thread -> row tid>>2, phys slot
    // tid&3; dest = bufOff + tid*16 + chunk*8192 (lane stride 16, wave-uniform
    // chunk base). Source pre-swizzled: logical slot = (tid&3) ^ fS,
    // fS = (tid>>3)&3 = (row>>1)&3 for both row and row+128.
    const int srowp = tid >> 2;                   // 0..127
    const int fS    = (tid >> 3) & 3;
    const int csrc  = ((tid & 3) ^ fS) * 16;
    const uint8_t* pA0 = A4 + (size_t)(m0 + srowp)       * KB2 + csrc;
    const uint8_t* pA1 = A4 + (size_t)(m0 + 128 + srowp) * KB2 + csrc;
    const uint8_t* pB0 = B4 + (size_t)(n0 + srowp)       * KB2 + csrc;
    const uint8_t* pB1 = B4 + (size_t)(n0 + 128 + srowp) * KB2 + csrc;

#define STAGE(bufOff) do {                                                     \
        gload16(pA0, lds + (bufOff) + tid * 16);                               \
        gload16(pA1, lds + (bufOff) + 8192  + tid * 16);                       \
        gload16(pB0, lds + (bufOff) + 16384 + tid * 16);                       \
        gload16(pB1, lds + (bufOff) + 24576 + tid * 16);                       \
        pA0 += BKB; pA1 += BKB; pB0 += BKB; pB1 += BKB;                        \
    } while (0)

    // ---- fragment read bases: row = wr*128 + mf*16 + l15 (A), wc*64+nf*16+l15
    // (B); (row>>1)&3 = (l15>>1)&3 (16-multiples vanish mod 4 after >>1).
    const int fR = (l15 >> 1) & 3;
    const int aBase = (wr * 128 + l15) * 64 + ((g ^ fR) * 16);
    const int bBase = 16384 + (wc * 64 + l15) * 64 + ((g ^ fR) * 16);

    f32x4 acc[8][4];
#pragma unroll
    for (int m = 0; m < 8; ++m)
#pragma unroll
        for (int n = 0; n < 4; ++n) acc[m][n] = (f32x4){0.f, 0.f, 0.f, 0.f};

    // B expanded once (4 resident 8-tuples); A expanded JIT, one-ahead read.
#define COMPUTE(bufOff) do {                                                   \
        const uint8_t* bp_ = lds + (bufOff);                                   \
        i32x8 b8_0 = pad8(*(const i32x4*)(bp_ + bBase));                       \
        i32x8 b8_1 = pad8(*(const i32x4*)(bp_ + bBase + 1024));                \
        i32x8 b8_2 = pad8(*(const i32x4*)(bp_ + bBase + 2048));                \
        i32x8 b8_3 = pad8(*(const i32x4*)(bp_ + bBase + 3072));                \
        i32x4 aN = *(const i32x4*)(bp_ + aBase);                               \
        __builtin_amdgcn_s_setprio(1);                                         \
        _Pragma("unroll")                                                      \
        for (int mf = 0; mf < 8; ++mf) {                                       \
            i32x8 a8 = pad8(aN);                                               \
            if (mf < 7) aN = *(const i32x4*)(bp_ + aBase + (mf + 1) * 1024);   \
            acc[mf][0] = MFMA_FP4(a8, b8_0, acc[mf][0]);                       \
            acc[mf][1] = MFMA_FP4(a8, b8_1, acc[mf][1]);                       \
            acc[mf][2] = MFMA_FP4(a8, b8_2, acc[mf][2]);                       \
            acc[mf][3] = MFMA_FP4(a8, b8_3, acc[mf][3]);                       \
        }                                                                      \
        __builtin_amdgcn_s_setprio(0);                                         \
    } while (0)

    // counted-vmcnt sync: retire oldest loads down to N, then raw barrier.
    // sched_barrier(0) pins compile-time motion (keeps vmcnt groups exact).
#define SYNC(n) do {                                                           \
        __builtin_amdgcn_sched_barrier(0);                                     \
        asm volatile("s_waitcnt vmcnt(" #n ")" ::: "memory");                  \
        __builtin_amdgcn_s_barrier();                                          \
        __builtin_amdgcn_sched_barrier(0);                                     \
    } while (0)

    // prologue: stage tiles 0,1,2 (12 loads in flight), wait tile 0 (vmcnt 8)
    STAGE(0);
    STAGE(BUFSZ);
    STAGE(2 * BUFSZ);
    SYNC(8);

    // steady state t=0..28: stage t+3, compute t, retire t+1's loads (vmcnt 8)
#pragma unroll 1
    for (int t = 0; t < NT - 3; ++t) {
        STAGE(((t + 3) & 3) * BUFSZ);
        COMPUTE((t & 3) * BUFSZ);
        SYNC(8);
    }
    // tail: t=29,30,31 (bufs 1,2,3); counted drain 4 -> 0
    COMPUTE(1 * BUFSZ);
    SYNC(4);
    COMPUTE(2 * BUFSZ);
    SYNC(0);
    COMPUTE(3 * BUFSZ);

    // epilogue: C/D 16x16 layout: col = lane&15, row = (lane>>4)*4 + reg
#pragma unroll
    for (int mf = 0; mf < 8; ++mf) {
#pragma unroll
        for (int nf = 0; nf < 4; ++nf) {
            size_t cc = (size_t)(n0 + wc * 64 + nf * 16 + l15);
            int rbase = m0 + wr * 128 + mf * 16 + g * 4;
#pragma unroll
            for (int reg = 0; reg < 4; ++reg)
                C[(size_t)(rbase + reg) * NDIM + cc] = acc[mf][nf][reg];
        }
    }
#undef STAGE
#undef COMPUTE
#undef SYNC
}

// =============================================================================
extern "C" void kernel_launch(void* const* d_in, const int* in_sizes, int n_in,
                              void* d_out, int out_size, void* d_ws, size_t ws_size,
                              hipStream_t stream) {
    const float* x = (const float*)d_in[0];   // [8192][4096]
    const float* w = (const float*)d_in[1];   // [4096][4096]
    float* out = (float*)d_out;               // [8192][4096]

    // workspace: A4 [M][K/2] (16 MiB) then B4T [N][K/2] (8 MiB)
    uint8_t* A4 = (uint8_t*)d_ws;
    uint8_t* B4 = (uint8_t*)d_ws + (size_t)MDIM * KB2;

    pack_a4_kernel<<<(int)((size_t)MDIM * KDIM / 16 / 256), 256, 0, stream>>>(x, A4);
    pack_b4t_kernel<<<dim3(NDIM / 64, KDIM / 64), 256, 0, stream>>>(w, B4);
    binmm_fp4_kernel<<<dim3(NDIM / BN, MDIM / BM), 512, 0, stream>>>(A4, B4, out);
}